// Round 6
// baseline (398.867 us; speedup 1.0000x reference)
//
#include <hip/hip_runtime.h>

#define B 64
#define N 2048
#define E 32768
#define D 256
#define H 256
#define ENT 100000
#define SEG 8          // edge segments per batch
#define EPB (E / SEG)  // 4096 edges per block
#define GCH 32
#define SLOTS 16       // max refs per entry (Poisson lambda=1.31 -> P(>16)~0)
#define GSB 256        // gather-scan blocks
#define ENT_PB ((ENT + GSB - 1) / GSB)   // 391 entries per scan block

// ---------------------------------------------------------------------------
// Zero the per-entry ref counter (100000 ints).
// ---------------------------------------------------------------------------
__global__ __launch_bounds__(512) void zero_cnt_kernel(int* __restrict__ cnt)
{
    const int i = blockIdx.x * 512 + threadIdx.x;
    if (i < ENT / 4) ((int4*)cnt)[i] = make_int4(0, 0, 0, 0);
}

// ---------------------------------------------------------------------------
// Inverted index build: for each (b,n), append flat index i=b*2048+n to the
// slot list of entry neighbors[i]. No sort/prefix-scan: fixed 16 slots/entry
// (max observed multiplicity ~10 for 131072 draws over 100000 entries).
// ---------------------------------------------------------------------------
__global__ __launch_bounds__(512) void scatter_kernel(
    const int* __restrict__ neighbors, int* __restrict__ cnt,
    unsigned int* __restrict__ slot)
{
    const int i = blockIdx.x * 512 + threadIdx.x;      // 256*512 = 131072 = B*N
    const int e = neighbors[i];
    const int p = atomicAdd(&cnt[e], 1);
    if (p < SLOTS) slot[(size_t)e * SLOTS + p] = (unsigned int)i;
}

// ---------------------------------------------------------------------------
// Edge pass 1 (R0 measured-best): w_part[b,seg,n], sw_part[b,seg].
// ---------------------------------------------------------------------------
__global__ __launch_bounds__(512) void edge_w_kernel(
    const int* __restrict__ adj_row, const int* __restrict__ adj_col,
    const float* __restrict__ adj_val, const int* __restrict__ cur_len,
    float* __restrict__ w_part, float* __restrict__ sw_part)
{
    __shared__ float wloc[N];
    __shared__ float sred[8];
    const int b = blockIdx.x, seg = blockIdx.y, tid = threadIdx.x;
    const int L = *cur_len;

    ((float4*)wloc)[tid] = make_float4(0.f, 0.f, 0.f, 0.f);
    __syncthreads();

    const int base = b * E + seg * EPB;
    const int4*   row4 = (const int4*)  (adj_row + base);
    const int4*   col4 = (const int4*)  (adj_col + base);
    const float4* val4 = (const float4*)(adj_val + base);

    float svp = 0.f;
    #pragma unroll
    for (int k = 0; k < EPB / (512 * 4); ++k) {    // 2 iterations
        const int    i = tid + k * 512;
        const int4   r = row4[i];
        const int4   c = col4[i];
        const float4 v = val4[i];
        if (r.x < L) { atomicAdd(&wloc[c.x], v.x); svp += v.x; }
        if (r.y < L) { atomicAdd(&wloc[c.y], v.y); svp += v.y; }
        if (r.z < L) { atomicAdd(&wloc[c.z], v.z); svp += v.z; }
        if (r.w < L) { atomicAdd(&wloc[c.w], v.w); svp += v.w; }
    }
    __syncthreads();

    float4* dst = (float4*)(w_part + ((size_t)b * SEG + seg) * N);
    dst[tid] = ((const float4*)wloc)[tid];

    for (int off = 32; off; off >>= 1) svp += __shfl_down(svp, off, 64);
    if ((tid & 63) == 0) sred[tid >> 6] = svp;
    __syncthreads();
    if (tid == 0) {
        float s = 0.f;
        #pragma unroll
        for (int i = 0; i < 8; ++i) s += sred[i];
        sw_part[b * SEG + seg] = s;
    }
}

// ---------------------------------------------------------------------------
// Edge pass 2 (R0 measured-best): rebuild w[b,:] from 8 partials, then
// z_part[b,seg,m] = sum_{e in seg: col==m} w[row[e]] * val[e].
// ---------------------------------------------------------------------------
__global__ __launch_bounds__(512) void edge_z_kernel(
    const int* __restrict__ adj_row, const int* __restrict__ adj_col,
    const float* __restrict__ adj_val, const float* __restrict__ w_part,
    float* __restrict__ z_part)
{
    __shared__ float wfull[N];
    __shared__ float zloc[N];
    const int b = blockIdx.x, seg = blockIdx.y, tid = threadIdx.x;

    const float4* wp4 = (const float4*)(w_part + (size_t)b * SEG * N);
    float4 s = make_float4(0.f, 0.f, 0.f, 0.f);
    #pragma unroll
    for (int sg = 0; sg < SEG; ++sg) {
        const float4 v = wp4[sg * (N / 4) + tid];
        s.x += v.x; s.y += v.y; s.z += v.z; s.w += v.w;
    }
    ((float4*)wfull)[tid] = s;
    ((float4*)zloc)[tid]  = make_float4(0.f, 0.f, 0.f, 0.f);
    __syncthreads();

    const int base = b * E + seg * EPB;
    const int4*   row4 = (const int4*)  (adj_row + base);
    const int4*   col4 = (const int4*)  (adj_col + base);
    const float4* val4 = (const float4*)(adj_val + base);

    #pragma unroll
    for (int k = 0; k < EPB / (512 * 4); ++k) {    // 2 iterations
        const int    i = tid + k * 512;
        const int4   r = row4[i];
        const int4   c = col4[i];
        const float4 v = val4[i];
        float wv;
        wv = wfull[r.x]; if (wv != 0.f) atomicAdd(&zloc[c.x], wv * v.x);
        wv = wfull[r.y]; if (wv != 0.f) atomicAdd(&zloc[c.y], wv * v.y);
        wv = wfull[r.z]; if (wv != 0.f) atomicAdd(&zloc[c.z], wv * v.z);
        wv = wfull[r.w]; if (wv != 0.f) atomicAdd(&zloc[c.w], wv * v.w);
    }
    __syncthreads();

    float4* dst = (float4*)(z_part + ((size_t)b * SEG + seg) * N);
    dst[tid] = ((const float4*)zloc)[tid];
}

// ---------------------------------------------------------------------------
// Gather-scan: replaces the random gather. Each block owns an ASCENDING
// 391-entry window of the emb table; reads only referenced rows (ascending
// addresses -> DRAM row-buffer hits, unlike the random 1KB reads that ran at
// ~2 TB/s). For each ref (b,n) of entry e: u_acc[b] += z[b,n]*emb[e], where
// z[b,n] is summed from the 8 z_part partials inline (L2-resident, wave-
// uniform loads). u_acc[64][256] f32 = 64 KB LDS, stored as [4][b][64] so
// lane L's 4 floats hit banks L%32 (2 lanes/bank = free). Plain-store one
// partial per block; head reduces the 256 partials.
// ---------------------------------------------------------------------------
__global__ __launch_bounds__(512) void gather_scan_kernel(
    const int* __restrict__ cnt, const unsigned int* __restrict__ slot,
    const float* __restrict__ z_part, const float* __restrict__ emb,
    float* __restrict__ u_pp)
{
    __shared__ float uacc[4][B][64];     // element d of row b at [d&3][b][d>>2]
    const int k = blockIdx.x, tid = threadIdx.x;
    const int wv = tid >> 6, lane = tid & 63;

    for (int x = tid; x < 4 * B * 64; x += 512) ((float*)uacc)[x] = 0.f;
    __syncthreads();

    const float4* __restrict__ emb4 = (const float4*)emb;
    const int e0 = k * ENT_PB;
    const int e1 = min(e0 + ENT_PB, ENT);

    // wave wv covers entries e0+wv+8m; process two (m even/odd) per iter for MLP
    for (int e = e0 + wv; e < e1; e += 16) {
        const int eB = e + 8;
        const int cA = min(cnt[e], SLOTS);
        const int cB = (eB < e1) ? min(cnt[eB], SLOTS) : 0;
        float4 rA = make_float4(0.f, 0.f, 0.f, 0.f), rB = rA;
        if (cA) rA = emb4[(size_t)e  * (D / 4) + lane];
        if (cB) rB = emb4[(size_t)eB * (D / 4) + lane];

        for (int r = 0; r < cA; ++r) {
            const unsigned int pl = slot[(size_t)e * SLOTS + r];
            const int pb = pl >> 11, pn = pl & 2047;
            const float* zp = z_part + (size_t)pb * (SEG * N) + pn;
            float zv = 0.f;
            #pragma unroll
            for (int sg = 0; sg < SEG; ++sg) zv += zp[sg * N];
            atomicAdd(&uacc[0][pb][lane], zv * rA.x);
            atomicAdd(&uacc[1][pb][lane], zv * rA.y);
            atomicAdd(&uacc[2][pb][lane], zv * rA.z);
            atomicAdd(&uacc[3][pb][lane], zv * rA.w);
        }
        for (int r = 0; r < cB; ++r) {
            const unsigned int pl = slot[(size_t)eB * SLOTS + r];
            const int pb = pl >> 11, pn = pl & 2047;
            const float* zp = z_part + (size_t)pb * (SEG * N) + pn;
            float zv = 0.f;
            #pragma unroll
            for (int sg = 0; sg < SEG; ++sg) zv += zp[sg * N];
            atomicAdd(&uacc[0][pb][lane], zv * rB.x);
            atomicAdd(&uacc[1][pb][lane], zv * rB.y);
            atomicAdd(&uacc[2][pb][lane], zv * rB.z);
            atomicAdd(&uacc[3][pb][lane], zv * rB.w);
        }
    }
    __syncthreads();

    for (int x = tid; x < B * D; x += 512) {
        const int bb = x >> 8, d = x & 255;
        u_pp[((size_t)k * B + bb) * D + d] = uacc[d & 3][bb][d >> 2];
    }
}

// ---------------------------------------------------------------------------
// Head: stage 1 now reduces the 256 gather-scan partials (u_pp[k][b][d]);
// rest unchanged (measured best).
// ---------------------------------------------------------------------------
__global__ __launch_bounds__(1024) void head_kernel(
    const float* __restrict__ u_pp, const float* __restrict__ sw_part,
    const float* __restrict__ W1, const float* __restrict__ b1,
    const float* __restrict__ W2, const float* __restrict__ b2,
    const float* __restrict__ fc1_w, const float* __restrict__ fc1_b,
    const int* __restrict__ cur_len, float* __restrict__ out)
{
    const int b = blockIdx.x;
    const int t = threadIdx.x & 255;   // output column
    const int s = threadIdx.x >> 8;    // k-split group (0..3)
    __shared__ float red[4][256];
    __shared__ float su[D];
    __shared__ float sy[H];
    __shared__ float sp[H];

    float part = 0.f;
    #pragma unroll 8
    for (int kk = s * (GSB / 4); kk < (s + 1) * (GSB / 4); ++kk)
        part += u_pp[((size_t)kk * B + b) * D + t];
    red[s][t] = part;
    __syncthreads();
    if (s == 0) su[t] = red[0][t] + red[1][t] + red[2][t] + red[3][t];
    __syncthreads();

    part = 0.f;
    #pragma unroll 8
    for (int k = 0; k < 64; ++k) {
        const int d = s * 64 + k;
        part += su[d] * W1[d * H + t];
    }
    red[s][t] = part;
    __syncthreads();
    if (s == 0) {
        float sw = 0.f;
        #pragma unroll
        for (int i = 0; i < SEG; ++i) sw += sw_part[b * SEG + i];
        sy[t] = red[0][t] + red[1][t] + red[2][t] + red[3][t] + sw * b1[t];
    }
    __syncthreads();

    const float invL = 1.f / (float)(*cur_len);
    part = 0.f;
    #pragma unroll 8
    for (int k = 0; k < 64; ++k) {
        const int d = s * 64 + k;
        part += sy[d] * W2[d * H + t];
    }
    red[s][t] = part;
    __syncthreads();
    if (s == 0)
        sp[t] = (red[0][t] + red[1][t] + red[2][t] + red[3][t]) * invL + b2[t];
    __syncthreads();

    part = 0.f;
    #pragma unroll 8
    for (int k = 0; k < 64; ++k) {
        const int d = s * 64 + k;
        part += sp[d] * fc1_w[d * H + t];
    }
    red[s][t] = part;
    __syncthreads();
    if (s == 0) {
        const float v = red[0][t] + red[1][t] + red[2][t] + red[3][t] + fc1_b[t];
        out[(size_t)b * H + t] = fmaxf(v, 0.f);
    }
}

extern "C" void kernel_launch(void* const* d_in, const int* in_sizes, int n_in,
                              void* d_out, int out_size, void* d_ws, size_t ws_size,
                              hipStream_t stream) {
    const int*   neighbors = (const int*)  d_in[0];
    const int*   adj_row   = (const int*)  d_in[1];
    const int*   adj_col   = (const int*)  d_in[2];
    const float* adj_val   = (const float*)d_in[3];
    const float* emb_table = (const float*)d_in[4];
    const float* W1        = (const float*)d_in[5];
    const float* b1        = (const float*)d_in[6];
    const float* W2        = (const float*)d_in[7];
    const float* b2        = (const float*)d_in[8];
    const float* fc1_w     = (const float*)d_in[9];
    const float* fc1_b     = (const float*)d_in[10];
    const int*   cur_len   = (const int*)  d_in[11];
    float*       out       = (float*)d_out;

    // workspace layout (floats):
    // [w_part: B*SEG*N][z_part: B*SEG*N][sw_part: B*SEG]
    // [u_pp: GSB*B*D][cnt: ENT ints][slot: ENT*SLOTS u32]
    float* wp_ws = (float*)d_ws;
    float* zp_ws = wp_ws + (size_t)B * SEG * N;
    float* sw_ws = zp_ws + (size_t)B * SEG * N;
    float* up_ws = sw_ws + (size_t)B * SEG;           // 16B-aligned
    int*   cnt_ws  = (int*)(up_ws + (size_t)GSB * B * D);
    unsigned int* slot_ws = (unsigned int*)(cnt_ws + ENT);

    zero_cnt_kernel<<<(ENT / 4 + 511) / 512, 512, 0, stream>>>(cnt_ws);
    scatter_kernel<<<(B * N) / 512, 512, 0, stream>>>(neighbors, cnt_ws, slot_ws);
    edge_w_kernel<<<dim3(B, SEG), 512, 0, stream>>>(adj_row, adj_col, adj_val,
                                                    cur_len, wp_ws, sw_ws);
    edge_z_kernel<<<dim3(B, SEG), 512, 0, stream>>>(adj_row, adj_col, adj_val,
                                                    wp_ws, zp_ws);
    gather_scan_kernel<<<GSB, 512, 0, stream>>>(cnt_ws, slot_ws, zp_ws,
                                                emb_table, up_ws);
    head_kernel<<<B, 1024, 0, stream>>>(up_ws, sw_ws, W1, b1, W2, b2,
                                        fc1_w, fc1_b, cur_len, out);
}

// Round 7
// 330.982 us; speedup vs baseline: 1.2051x; 1.2051x over previous
//
#include <hip/hip_runtime.h>

#define B 64
#define N 2048
#define E 32768
#define D 256
#define H 256
#define ENT 100000
#define SEG 8          // edge segments per batch
#define EPB (E / SEG)  // 4096 edges per block
#define KPAD 100352    // 256 * 392 (Z columns, padded past ENT; pad stays zero)
#define KCH 392        // k-chunk per gemm block
#define GB 256         // gemm blocks (1 per CU)
#define Z4PB 3136      // float4s of Z zeroed per edge_w block (B*KPAD/4/512)

// ---------------------------------------------------------------------------
// Edge pass 1 (R0 measured-best) + folded Z-zero.
// R5 showed the edge kernels have ~4 TB/s of spare BW (102 MB warm stream
// added only ~8 us), so zeroing Z (25.7 MB) here is ~2 us and saves a launch.
// ---------------------------------------------------------------------------
__global__ __launch_bounds__(512) void edge_w_kernel(
    const int* __restrict__ adj_row, const int* __restrict__ adj_col,
    const float* __restrict__ adj_val, const int* __restrict__ cur_len,
    float* __restrict__ Z, float* __restrict__ w_part,
    float* __restrict__ sw_part)
{
    __shared__ float wloc[N];
    __shared__ float sred[8];
    const int b = blockIdx.x, seg = blockIdx.y, tid = threadIdx.x;
    const int L = *cur_len;

    // zero this block's slice of Z (fire-and-forget stores)
    {
        float4* z4 = (float4*)Z + (size_t)(b * SEG + seg) * Z4PB;
        #pragma unroll
        for (int k = 0; k < 7; ++k) {
            const int x = tid + k * 512;
            if (x < Z4PB) z4[x] = make_float4(0.f, 0.f, 0.f, 0.f);
        }
    }

    ((float4*)wloc)[tid] = make_float4(0.f, 0.f, 0.f, 0.f);
    __syncthreads();

    const int base = b * E + seg * EPB;
    const int4*   row4 = (const int4*)  (adj_row + base);
    const int4*   col4 = (const int4*)  (adj_col + base);
    const float4* val4 = (const float4*)(adj_val + base);

    float svp = 0.f;
    #pragma unroll
    for (int k = 0; k < EPB / (512 * 4); ++k) {    // 2 iterations
        const int    i = tid + k * 512;
        const int4   r = row4[i];
        const int4   c = col4[i];
        const float4 v = val4[i];
        if (r.x < L) { atomicAdd(&wloc[c.x], v.x); svp += v.x; }
        if (r.y < L) { atomicAdd(&wloc[c.y], v.y); svp += v.y; }
        if (r.z < L) { atomicAdd(&wloc[c.z], v.z); svp += v.z; }
        if (r.w < L) { atomicAdd(&wloc[c.w], v.w); svp += v.w; }
    }
    __syncthreads();

    float4* dst = (float4*)(w_part + ((size_t)b * SEG + seg) * N);
    dst[tid] = ((const float4*)wloc)[tid];

    for (int off = 32; off; off >>= 1) svp += __shfl_down(svp, off, 64);
    if ((tid & 63) == 0) sred[tid >> 6] = svp;
    __syncthreads();
    if (tid == 0) {
        float s = 0.f;
        #pragma unroll
        for (int i = 0; i < 8; ++i) s += sred[i];
        sw_part[b * SEG + seg] = s;
    }
}

// ---------------------------------------------------------------------------
// Edge pass 2 (R0 measured-best): rebuild w[b,:] from 8 partials, then
// z_part[b,seg,m] = sum_{e in seg: col==m} w[row[e]] * val[e].
// ---------------------------------------------------------------------------
__global__ __launch_bounds__(512) void edge_z_kernel(
    const int* __restrict__ adj_row, const int* __restrict__ adj_col,
    const float* __restrict__ adj_val, const float* __restrict__ w_part,
    float* __restrict__ z_part)
{
    __shared__ float wfull[N];
    __shared__ float zloc[N];
    const int b = blockIdx.x, seg = blockIdx.y, tid = threadIdx.x;

    const float4* wp4 = (const float4*)(w_part + (size_t)b * SEG * N);
    float4 s = make_float4(0.f, 0.f, 0.f, 0.f);
    #pragma unroll
    for (int sg = 0; sg < SEG; ++sg) {
        const float4 v = wp4[sg * (N / 4) + tid];
        s.x += v.x; s.y += v.y; s.z += v.z; s.w += v.w;
    }
    ((float4*)wfull)[tid] = s;
    ((float4*)zloc)[tid]  = make_float4(0.f, 0.f, 0.f, 0.f);
    __syncthreads();

    const int base = b * E + seg * EPB;
    const int4*   row4 = (const int4*)  (adj_row + base);
    const int4*   col4 = (const int4*)  (adj_col + base);
    const float4* val4 = (const float4*)(adj_val + base);

    #pragma unroll
    for (int k = 0; k < EPB / (512 * 4); ++k) {    // 2 iterations
        const int    i = tid + k * 512;
        const int4   r = row4[i];
        const int4   c = col4[i];
        const float4 v = val4[i];
        float wv;
        wv = wfull[r.x]; if (wv != 0.f) atomicAdd(&zloc[c.x], wv * v.x);
        wv = wfull[r.y]; if (wv != 0.f) atomicAdd(&zloc[c.y], wv * v.y);
        wv = wfull[r.z]; if (wv != 0.f) atomicAdd(&zloc[c.z], wv * v.z);
        wv = wfull[r.w]; if (wv != 0.f) atomicAdd(&zloc[c.w], wv * v.w);
    }
    __syncthreads();

    float4* dst = (float4*)(z_part + ((size_t)b * SEG + seg) * N);
    dst[tid] = ((const float4*)zloc)[tid];
}

// ---------------------------------------------------------------------------
// Scatter: Z[b][neighbors[b,n]] += sum_sg z_part[b,sg,n]. 131072 threads,
// one global atomicAdd each (collisions only for duplicate (b,entry) pairs).
// ---------------------------------------------------------------------------
__global__ __launch_bounds__(512) void scatter_kernel(
    const int* __restrict__ neighbors, const float* __restrict__ z_part,
    float* __restrict__ Z)
{
    const int i = blockIdx.x * 512 + threadIdx.x;   // 256 blocks -> B*N
    const int b = i >> 11, n = i & 2047;
    const float* zp = z_part + (size_t)b * (SEG * N) + n;
    float zv = 0.f;
    #pragma unroll
    for (int sg = 0; sg < SEG; ++sg) zv += zp[sg * N];
    atomicAdd(&Z[(size_t)b * KPAD + neighbors[i]], zv);
}

// ---------------------------------------------------------------------------
// Dense GEMM replaces the random gather: u_pp[blk] = Z[:, k-range] @ emb[k-range].
// emb is streamed SEQUENTIALLY (each row read by exactly one block) -> avoids
// the ~2 TB/s random-1KB ceiling (R4 MLP-null, R5 warm-null). No LDS, no
// barriers, no atomics in the hot loop: 256 blocks x 256 thr, thread owns
// (b-group g: 16 rows) x (d-quad q: 4 cols) = 64 f32 accumulators; per k4
// step: 16 wave-uniform float4 Z loads + 4 coalesced emb row loads + 256 FMA.
// VALU floor 20.8 us; E-stream 102 MB.
// ---------------------------------------------------------------------------
__global__ __launch_bounds__(256) void gemm_kernel(
    const float* __restrict__ Z, const float* __restrict__ emb,
    float* __restrict__ u_pp)
{
    const int blk = blockIdx.x;          // 0..255
    const int g   = threadIdx.x >> 6;    // b-group (b = g*16+i)
    const int q   = threadIdx.x & 63;    // d-quad
    const int k0  = blk * KCH;
    const float4* __restrict__ e4 = (const float4*)emb;

    float4 acc[16];
    #pragma unroll
    for (int i = 0; i < 16; ++i) acc[i] = make_float4(0.f, 0.f, 0.f, 0.f);

    const float* __restrict__ zb = Z + (size_t)(g * 16) * KPAD + k0;

    for (int k = 0; k < KCH; k += 4) {
        const int kk = k0 + k;
        float4 a[16];
        #pragma unroll
        for (int i = 0; i < 16; ++i)
            a[i] = *(const float4*)(zb + (size_t)i * KPAD + k);
        float4 e0_ = make_float4(0.f,0.f,0.f,0.f), e1_ = e0_, e2_ = e0_, e3_ = e0_;
        if (kk + 0 < ENT) e0_ = e4[(size_t)(kk + 0) * (D / 4) + q];
        if (kk + 1 < ENT) e1_ = e4[(size_t)(kk + 1) * (D / 4) + q];
        if (kk + 2 < ENT) e2_ = e4[(size_t)(kk + 2) * (D / 4) + q];
        if (kk + 3 < ENT) e3_ = e4[(size_t)(kk + 3) * (D / 4) + q];
        #pragma unroll
        for (int i = 0; i < 16; ++i) {
            acc[i].x += a[i].x*e0_.x + a[i].y*e1_.x + a[i].z*e2_.x + a[i].w*e3_.x;
            acc[i].y += a[i].x*e0_.y + a[i].y*e1_.y + a[i].z*e2_.y + a[i].w*e3_.y;
            acc[i].z += a[i].x*e0_.z + a[i].y*e1_.z + a[i].z*e2_.z + a[i].w*e3_.z;
            acc[i].w += a[i].x*e0_.w + a[i].y*e1_.w + a[i].z*e2_.w + a[i].w*e3_.w;
        }
    }

    float4* dst = (float4*)u_pp + (size_t)blk * (B * D / 4);
    #pragma unroll
    for (int i = 0; i < 16; ++i)
        dst[(g * 16 + i) * (D / 4) + q] = acc[i];
}

// ---------------------------------------------------------------------------
// Head: stage 1 reduces the 256 GEMM partials; stages 2-4 unchanged.
// ---------------------------------------------------------------------------
__global__ __launch_bounds__(1024) void head_kernel(
    const float* __restrict__ u_pp, const float* __restrict__ sw_part,
    const float* __restrict__ W1, const float* __restrict__ b1,
    const float* __restrict__ W2, const float* __restrict__ b2,
    const float* __restrict__ fc1_w, const float* __restrict__ fc1_b,
    const int* __restrict__ cur_len, float* __restrict__ out)
{
    const int b = blockIdx.x;
    const int t = threadIdx.x & 255;   // output column
    const int s = threadIdx.x >> 8;    // k-split group (0..3)
    __shared__ float red[4][256];
    __shared__ float su[D];
    __shared__ float sy[H];
    __shared__ float sp[H];

    float part = 0.f;
    #pragma unroll 8
    for (int c = s * (GB / 4); c < (s + 1) * (GB / 4); ++c)
        part += u_pp[(size_t)c * (B * D) + b * D + t];
    red[s][t] = part;
    __syncthreads();
    if (s == 0) su[t] = red[0][t] + red[1][t] + red[2][t] + red[3][t];
    __syncthreads();

    part = 0.f;
    #pragma unroll 8
    for (int k = 0; k < 64; ++k) {
        const int d = s * 64 + k;
        part += su[d] * W1[d * H + t];
    }
    red[s][t] = part;
    __syncthreads();
    if (s == 0) {
        float sw = 0.f;
        #pragma unroll
        for (int i = 0; i < SEG; ++i) sw += sw_part[b * SEG + i];
        sy[t] = red[0][t] + red[1][t] + red[2][t] + red[3][t] + sw * b1[t];
    }
    __syncthreads();

    const float invL = 1.f / (float)(*cur_len);
    part = 0.f;
    #pragma unroll 8
    for (int k = 0; k < 64; ++k) {
        const int d = s * 64 + k;
        part += sy[d] * W2[d * H + t];
    }
    red[s][t] = part;
    __syncthreads();
    if (s == 0)
        sp[t] = (red[0][t] + red[1][t] + red[2][t] + red[3][t]) * invL + b2[t];
    __syncthreads();

    part = 0.f;
    #pragma unroll 8
    for (int k = 0; k < 64; ++k) {
        const int d = s * 64 + k;
        part += sp[d] * fc1_w[d * H + t];
    }
    red[s][t] = part;
    __syncthreads();
    if (s == 0) {
        const float v = red[0][t] + red[1][t] + red[2][t] + red[3][t] + fc1_b[t];
        out[(size_t)b * H + t] = fmaxf(v, 0.f);
    }
}

extern "C" void kernel_launch(void* const* d_in, const int* in_sizes, int n_in,
                              void* d_out, int out_size, void* d_ws, size_t ws_size,
                              hipStream_t stream) {
    const int*   neighbors = (const int*)  d_in[0];
    const int*   adj_row   = (const int*)  d_in[1];
    const int*   adj_col   = (const int*)  d_in[2];
    const float* adj_val   = (const float*)d_in[3];
    const float* emb_table = (const float*)d_in[4];
    const float* W1        = (const float*)d_in[5];
    const float* b1        = (const float*)d_in[6];
    const float* W2        = (const float*)d_in[7];
    const float* b2        = (const float*)d_in[8];
    const float* fc1_w     = (const float*)d_in[9];
    const float* fc1_b     = (const float*)d_in[10];
    const int*   cur_len   = (const int*)  d_in[11];
    float*       out       = (float*)d_out;

    // workspace layout (floats), ~50.5 MB total:
    // [w_part: B*SEG*N][z_part: B*SEG*N][sw_part: B*SEG]
    // [Z: B*KPAD (zeroed in edge_w)][u_pp: GB*B*D]
    float* wp_ws = (float*)d_ws;
    float* zp_ws = wp_ws + (size_t)B * SEG * N;
    float* sw_ws = zp_ws + (size_t)B * SEG * N;
    float* Z_ws  = sw_ws + (size_t)B * SEG;           // 16B-aligned (B*SEG=512)
    float* up_ws = Z_ws  + (size_t)B * KPAD;

    edge_w_kernel<<<dim3(B, SEG), 512, 0, stream>>>(adj_row, adj_col, adj_val,
                                                    cur_len, Z_ws, wp_ws, sw_ws);
    edge_z_kernel<<<dim3(B, SEG), 512, 0, stream>>>(adj_row, adj_col, adj_val,
                                                    wp_ws, zp_ws);
    scatter_kernel<<<(B * N) / 512, 512, 0, stream>>>(neighbors, zp_ws, Z_ws);
    gemm_kernel<<<GB, 256, 0, stream>>>(Z_ws, emb_table, up_ws);
    head_kernel<<<B, 1024, 0, stream>>>(up_ws, sw_ws, W1, b1, W2, b2,
                                        fc1_w, fc1_b, cur_len, out);
}

// Round 8
// 310.368 us; speedup vs baseline: 1.2851x; 1.0664x over previous
//
#include <hip/hip_runtime.h>

#define B 64
#define N 2048
#define E 32768
#define D 256
#define H 256
#define ENT 100000
#define SEG 8          // edge segments per batch
#define EPB (E / SEG)  // 4096 edges per block
#define KPAD 100352    // 512 * 196 (Z columns, padded past ENT; pad stays zero)
#define KCH 196        // k-chunk per gemm block
#define GB 512         // gemm blocks (2 per CU -> 16 waves/CU)
#define Z4PB 3136      // float4s of Z zeroed per edge_w block (B*KPAD/4/512)

// ---------------------------------------------------------------------------
// Edge pass 1 (R0 measured-best) + folded Z-zero (R7, worked fine).
// ---------------------------------------------------------------------------
__global__ __launch_bounds__(512) void edge_w_kernel(
    const int* __restrict__ adj_row, const int* __restrict__ adj_col,
    const float* __restrict__ adj_val, const int* __restrict__ cur_len,
    float* __restrict__ Z, float* __restrict__ w_part,
    float* __restrict__ sw_part)
{
    __shared__ float wloc[N];
    __shared__ float sred[8];
    const int b = blockIdx.x, seg = blockIdx.y, tid = threadIdx.x;
    const int L = *cur_len;

    // zero this block's slice of Z (fire-and-forget stores)
    {
        float4* z4 = (float4*)Z + (size_t)(b * SEG + seg) * Z4PB;
        #pragma unroll
        for (int k = 0; k < 7; ++k) {
            const int x = tid + k * 512;
            if (x < Z4PB) z4[x] = make_float4(0.f, 0.f, 0.f, 0.f);
        }
    }

    ((float4*)wloc)[tid] = make_float4(0.f, 0.f, 0.f, 0.f);
    __syncthreads();

    const int base = b * E + seg * EPB;
    const int4*   row4 = (const int4*)  (adj_row + base);
    const int4*   col4 = (const int4*)  (adj_col + base);
    const float4* val4 = (const float4*)(adj_val + base);

    float svp = 0.f;
    #pragma unroll
    for (int k = 0; k < EPB / (512 * 4); ++k) {    // 2 iterations
        const int    i = tid + k * 512;
        const int4   r = row4[i];
        const int4   c = col4[i];
        const float4 v = val4[i];
        if (r.x < L) { atomicAdd(&wloc[c.x], v.x); svp += v.x; }
        if (r.y < L) { atomicAdd(&wloc[c.y], v.y); svp += v.y; }
        if (r.z < L) { atomicAdd(&wloc[c.z], v.z); svp += v.z; }
        if (r.w < L) { atomicAdd(&wloc[c.w], v.w); svp += v.w; }
    }
    __syncthreads();

    float4* dst = (float4*)(w_part + ((size_t)b * SEG + seg) * N);
    dst[tid] = ((const float4*)wloc)[tid];

    for (int off = 32; off; off >>= 1) svp += __shfl_down(svp, off, 64);
    if ((tid & 63) == 0) sred[tid >> 6] = svp;
    __syncthreads();
    if (tid == 0) {
        float s = 0.f;
        #pragma unroll
        for (int i = 0; i < 8; ++i) s += sred[i];
        sw_part[b * SEG + seg] = s;
    }
}

// ---------------------------------------------------------------------------
// Edge pass 2 (R0 measured-best): rebuild w[b,:] from 8 partials, then
// z_part[b,seg,m] = sum_{e in seg: col==m} w[row[e]] * val[e].
// ---------------------------------------------------------------------------
__global__ __launch_bounds__(512) void edge_z_kernel(
    const int* __restrict__ adj_row, const int* __restrict__ adj_col,
    const float* __restrict__ adj_val, const float* __restrict__ w_part,
    float* __restrict__ z_part)
{
    __shared__ float wfull[N];
    __shared__ float zloc[N];
    const int b = blockIdx.x, seg = blockIdx.y, tid = threadIdx.x;

    const float4* wp4 = (const float4*)(w_part + (size_t)b * SEG * N);
    float4 s = make_float4(0.f, 0.f, 0.f, 0.f);
    #pragma unroll
    for (int sg = 0; sg < SEG; ++sg) {
        const float4 v = wp4[sg * (N / 4) + tid];
        s.x += v.x; s.y += v.y; s.z += v.z; s.w += v.w;
    }
    ((float4*)wfull)[tid] = s;
    ((float4*)zloc)[tid]  = make_float4(0.f, 0.f, 0.f, 0.f);
    __syncthreads();

    const int base = b * E + seg * EPB;
    const int4*   row4 = (const int4*)  (adj_row + base);
    const int4*   col4 = (const int4*)  (adj_col + base);
    const float4* val4 = (const float4*)(adj_val + base);

    #pragma unroll
    for (int k = 0; k < EPB / (512 * 4); ++k) {    // 2 iterations
        const int    i = tid + k * 512;
        const int4   r = row4[i];
        const int4   c = col4[i];
        const float4 v = val4[i];
        float wv;
        wv = wfull[r.x]; if (wv != 0.f) atomicAdd(&zloc[c.x], wv * v.x);
        wv = wfull[r.y]; if (wv != 0.f) atomicAdd(&zloc[c.y], wv * v.y);
        wv = wfull[r.z]; if (wv != 0.f) atomicAdd(&zloc[c.z], wv * v.z);
        wv = wfull[r.w]; if (wv != 0.f) atomicAdd(&zloc[c.w], wv * v.w);
    }
    __syncthreads();

    float4* dst = (float4*)(z_part + ((size_t)b * SEG + seg) * N);
    dst[tid] = ((const float4*)zloc)[tid];
}

// ---------------------------------------------------------------------------
// Scatter: Z[b][neighbors[b,n]] += sum_sg z_part[b,sg,n]. 131072 threads,
// one global atomicAdd each.
// ---------------------------------------------------------------------------
__global__ __launch_bounds__(512) void scatter_kernel(
    const int* __restrict__ neighbors, const float* __restrict__ z_part,
    float* __restrict__ Z)
{
    const int i = blockIdx.x * 512 + threadIdx.x;   // 256 blocks -> B*N
    const int b = i >> 11, n = i & 2047;
    const float* zp = z_part + (size_t)b * (SEG * N) + n;
    float zv = 0.f;
    #pragma unroll
    for (int sg = 0; sg < SEG; ++sg) zv += zp[sg * N];
    atomicAdd(&Z[(size_t)b * KPAD + neighbors[i]], zv);
}

// ---------------------------------------------------------------------------
// Dense GEMM v2: u_pp[blk] = Z[:, k-range] @ emb[k-range].
// R7 ran this at 141 us with Occupancy 10.6% (1 block/CU = 1 wave/SIMD) and
// VALUBusy 26% -- latency-bound, not a concept failure. Fixes:
//  - 512 blocks x 512 threads (KCH=196): 16 waves/CU.
//  - 8 rows/thread (8 f4 acc, ~90 VGPR) instead of 16.
//  - wave-uniform sparsity skip: Z is ~98% zero; the 8 Z loads per k-quad are
//    wave-uniform, so a bits-nonzero test skips ~90% of 16-FMA bundles with a
//    divergence-free branch.
//  - block-level k clamp (kv % 4 == 0 always) -> no per-load ENT guards.
// ---------------------------------------------------------------------------
__global__ __launch_bounds__(512) void gemm_kernel(
    const float* __restrict__ Z, const float* __restrict__ emb,
    float* __restrict__ u_pp)
{
    const int blk = blockIdx.x;          // 0..511
    const int g   = threadIdx.x >> 6;    // row-group: rows g*8 .. g*8+7
    const int q   = threadIdx.x & 63;    // d-quad
    const int k0  = blk * KCH;
    const float4* __restrict__ e4 = (const float4*)emb;

    float4 acc[8];
    #pragma unroll
    for (int i = 0; i < 8; ++i) acc[i] = make_float4(0.f, 0.f, 0.f, 0.f);

    const float* __restrict__ zb = Z + (size_t)(g * 8) * KPAD + k0;

    int kv = ENT - k0;                       // valid entries in this chunk
    kv = kv < 0 ? 0 : (kv > KCH ? KCH : kv); // in {196, 40, 0} -> always %4==0

    for (int k = 0; k < kv; k += 4) {
        const int kk = k0 + k;
        float4 a[8];
        #pragma unroll
        for (int i = 0; i < 8; ++i)
            a[i] = *(const float4*)(zb + (size_t)i * KPAD + k);
        const float4 e0_ = e4[(size_t)(kk + 0) * (D / 4) + q];
        const float4 e1_ = e4[(size_t)(kk + 1) * (D / 4) + q];
        const float4 e2_ = e4[(size_t)(kk + 2) * (D / 4) + q];
        const float4 e3_ = e4[(size_t)(kk + 3) * (D / 4) + q];
        #pragma unroll
        for (int i = 0; i < 8; ++i) {
            const unsigned int nz =
                __float_as_uint(a[i].x) | __float_as_uint(a[i].y) |
                __float_as_uint(a[i].z) | __float_as_uint(a[i].w);
            if (nz) {   // wave-uniform (a[i] loads are lane-independent)
                acc[i].x += a[i].x*e0_.x + a[i].y*e1_.x + a[i].z*e2_.x + a[i].w*e3_.x;
                acc[i].y += a[i].x*e0_.y + a[i].y*e1_.y + a[i].z*e2_.y + a[i].w*e3_.y;
                acc[i].z += a[i].x*e0_.z + a[i].y*e1_.z + a[i].z*e2_.z + a[i].w*e3_.z;
                acc[i].w += a[i].x*e0_.w + a[i].y*e1_.w + a[i].z*e2_.w + a[i].w*e3_.w;
            }
        }
    }

    float4* dst = (float4*)u_pp + (size_t)blk * (B * D / 4);
    #pragma unroll
    for (int i = 0; i < 8; ++i)
        dst[(g * 8 + i) * (D / 4) + q] = acc[i];
}

// ---------------------------------------------------------------------------
// Head: stage 1 reduces the 512 GEMM partials; stages 2-4 unchanged.
// ---------------------------------------------------------------------------
__global__ __launch_bounds__(1024) void head_kernel(
    const float* __restrict__ u_pp, const float* __restrict__ sw_part,
    const float* __restrict__ W1, const float* __restrict__ b1,
    const float* __restrict__ W2, const float* __restrict__ b2,
    const float* __restrict__ fc1_w, const float* __restrict__ fc1_b,
    const int* __restrict__ cur_len, float* __restrict__ out)
{
    const int b = blockIdx.x;
    const int t = threadIdx.x & 255;   // output column
    const int s = threadIdx.x >> 8;    // k-split group (0..3)
    __shared__ float red[4][256];
    __shared__ float su[D];
    __shared__ float sy[H];
    __shared__ float sp[H];

    float part = 0.f;
    #pragma unroll 8
    for (int c = s * (GB / 4); c < (s + 1) * (GB / 4); ++c)
        part += u_pp[(size_t)c * (B * D) + b * D + t];
    red[s][t] = part;
    __syncthreads();
    if (s == 0) su[t] = red[0][t] + red[1][t] + red[2][t] + red[3][t];
    __syncthreads();

    part = 0.f;
    #pragma unroll 8
    for (int k = 0; k < 64; ++k) {
        const int d = s * 64 + k;
        part += su[d] * W1[d * H + t];
    }
    red[s][t] = part;
    __syncthreads();
    if (s == 0) {
        float sw = 0.f;
        #pragma unroll
        for (int i = 0; i < SEG; ++i) sw += sw_part[b * SEG + i];
        sy[t] = red[0][t] + red[1][t] + red[2][t] + red[3][t] + sw * b1[t];
    }
    __syncthreads();

    const float invL = 1.f / (float)(*cur_len);
    part = 0.f;
    #pragma unroll 8
    for (int k = 0; k < 64; ++k) {
        const int d = s * 64 + k;
        part += sy[d] * W2[d * H + t];
    }
    red[s][t] = part;
    __syncthreads();
    if (s == 0)
        sp[t] = (red[0][t] + red[1][t] + red[2][t] + red[3][t]) * invL + b2[t];
    __syncthreads();

    part = 0.f;
    #pragma unroll 8
    for (int k = 0; k < 64; ++k) {
        const int d = s * 64 + k;
        part += sp[d] * fc1_w[d * H + t];
    }
    red[s][t] = part;
    __syncthreads();
    if (s == 0) {
        const float v = red[0][t] + red[1][t] + red[2][t] + red[3][t] + fc1_b[t];
        out[(size_t)b * H + t] = fmaxf(v, 0.f);
    }
}

extern "C" void kernel_launch(void* const* d_in, const int* in_sizes, int n_in,
                              void* d_out, int out_size, void* d_ws, size_t ws_size,
                              hipStream_t stream) {
    const int*   neighbors = (const int*)  d_in[0];
    const int*   adj_row   = (const int*)  d_in[1];
    const int*   adj_col   = (const int*)  d_in[2];
    const float* adj_val   = (const float*)d_in[3];
    const float* emb_table = (const float*)d_in[4];
    const float* W1        = (const float*)d_in[5];
    const float* b1        = (const float*)d_in[6];
    const float* W2        = (const float*)d_in[7];
    const float* b2        = (const float*)d_in[8];
    const float* fc1_w     = (const float*)d_in[9];
    const float* fc1_b     = (const float*)d_in[10];
    const int*   cur_len   = (const int*)  d_in[11];
    float*       out       = (float*)d_out;

    // workspace layout (floats), ~67 MB total:
    // [w_part: B*SEG*N][z_part: B*SEG*N][sw_part: B*SEG]
    // [Z: B*KPAD (zeroed in edge_w)][u_pp: GB*B*D]
    float* wp_ws = (float*)d_ws;
    float* zp_ws = wp_ws + (size_t)B * SEG * N;
    float* sw_ws = zp_ws + (size_t)B * SEG * N;
    float* Z_ws  = sw_ws + (size_t)B * SEG;           // 16B-aligned (B*SEG=512)
    float* up_ws = Z_ws  + (size_t)B * KPAD;

    edge_w_kernel<<<dim3(B, SEG), 512, 0, stream>>>(adj_row, adj_col, adj_val,
                                                    cur_len, Z_ws, wp_ws, sw_ws);
    edge_z_kernel<<<dim3(B, SEG), 512, 0, stream>>>(adj_row, adj_col, adj_val,
                                                    wp_ws, zp_ws);
    scatter_kernel<<<(B * N) / 512, 512, 0, stream>>>(neighbors, zp_ws, Z_ws);
    gemm_kernel<<<GB, 512, 0, stream>>>(Z_ws, emb_table, up_ws);
    head_kernel<<<B, 1024, 0, stream>>>(up_ws, sw_ws, W1, b1, W2, b2,
                                        fc1_w, fc1_b, cur_len, out);
}

// Round 9
// 260.329 us; speedup vs baseline: 1.5322x; 1.1922x over previous
//
#include <hip/hip_runtime.h>

#define B 64
#define N 2048
#define E 32768
#define D 256
#define H 256
#define ENT 100000
#define SEG 8          // edge segments per batch
#define EPB (E / SEG)  // 4096 edges per block
#define KPAD 100352    // 512 * 196 (Z columns, padded past ENT; pad stays zero)
#define KCH 196        // k-chunk per gemm block
#define GB 512         // gemm blocks (2 per CU -> 16 waves/CU)
#define Z4PB 3136      // float4s of Z zeroed per edge_w block (B*KPAD/4/512)

// ---------------------------------------------------------------------------
// Edge pass 1 (R0 measured-best) + folded Z-zero (R7/R8, works fine).
// ---------------------------------------------------------------------------
__global__ __launch_bounds__(512) void edge_w_kernel(
    const int* __restrict__ adj_row, const int* __restrict__ adj_col,
    const float* __restrict__ adj_val, const int* __restrict__ cur_len,
    float* __restrict__ Z, float* __restrict__ w_part,
    float* __restrict__ sw_part)
{
    __shared__ float wloc[N];
    __shared__ float sred[8];
    const int b = blockIdx.x, seg = blockIdx.y, tid = threadIdx.x;
    const int L = *cur_len;

    // zero this block's slice of Z (fire-and-forget stores)
    {
        float4* z4 = (float4*)Z + (size_t)(b * SEG + seg) * Z4PB;
        #pragma unroll
        for (int k = 0; k < 7; ++k) {
            const int x = tid + k * 512;
            if (x < Z4PB) z4[x] = make_float4(0.f, 0.f, 0.f, 0.f);
        }
    }

    ((float4*)wloc)[tid] = make_float4(0.f, 0.f, 0.f, 0.f);
    __syncthreads();

    const int base = b * E + seg * EPB;
    const int4*   row4 = (const int4*)  (adj_row + base);
    const int4*   col4 = (const int4*)  (adj_col + base);
    const float4* val4 = (const float4*)(adj_val + base);

    float svp = 0.f;
    #pragma unroll
    for (int k = 0; k < EPB / (512 * 4); ++k) {    // 2 iterations
        const int    i = tid + k * 512;
        const int4   r = row4[i];
        const int4   c = col4[i];
        const float4 v = val4[i];
        if (r.x < L) { atomicAdd(&wloc[c.x], v.x); svp += v.x; }
        if (r.y < L) { atomicAdd(&wloc[c.y], v.y); svp += v.y; }
        if (r.z < L) { atomicAdd(&wloc[c.z], v.z); svp += v.z; }
        if (r.w < L) { atomicAdd(&wloc[c.w], v.w); svp += v.w; }
    }
    __syncthreads();

    float4* dst = (float4*)(w_part + ((size_t)b * SEG + seg) * N);
    dst[tid] = ((const float4*)wloc)[tid];

    for (int off = 32; off; off >>= 1) svp += __shfl_down(svp, off, 64);
    if ((tid & 63) == 0) sred[tid >> 6] = svp;
    __syncthreads();
    if (tid == 0) {
        float s = 0.f;
        #pragma unroll
        for (int i = 0; i < 8; ++i) s += sred[i];
        sw_part[b * SEG + seg] = s;
    }
}

// ---------------------------------------------------------------------------
// Edge pass 2 (R0 measured-best): rebuild w[b,:] from 8 partials, then
// z_part[b,seg,m] = sum_{e in seg: col==m} w[row[e]] * val[e].
// ---------------------------------------------------------------------------
__global__ __launch_bounds__(512) void edge_z_kernel(
    const int* __restrict__ adj_row, const int* __restrict__ adj_col,
    const float* __restrict__ adj_val, const float* __restrict__ w_part,
    float* __restrict__ z_part)
{
    __shared__ float wfull[N];
    __shared__ float zloc[N];
    const int b = blockIdx.x, seg = blockIdx.y, tid = threadIdx.x;

    const float4* wp4 = (const float4*)(w_part + (size_t)b * SEG * N);
    float4 s = make_float4(0.f, 0.f, 0.f, 0.f);
    #pragma unroll
    for (int sg = 0; sg < SEG; ++sg) {
        const float4 v = wp4[sg * (N / 4) + tid];
        s.x += v.x; s.y += v.y; s.z += v.z; s.w += v.w;
    }
    ((float4*)wfull)[tid] = s;
    ((float4*)zloc)[tid]  = make_float4(0.f, 0.f, 0.f, 0.f);
    __syncthreads();

    const int base = b * E + seg * EPB;
    const int4*   row4 = (const int4*)  (adj_row + base);
    const int4*   col4 = (const int4*)  (adj_col + base);
    const float4* val4 = (const float4*)(adj_val + base);

    #pragma unroll
    for (int k = 0; k < EPB / (512 * 4); ++k) {    // 2 iterations
        const int    i = tid + k * 512;
        const int4   r = row4[i];
        const int4   c = col4[i];
        const float4 v = val4[i];
        float wv;
        wv = wfull[r.x]; if (wv != 0.f) atomicAdd(&zloc[c.x], wv * v.x);
        wv = wfull[r.y]; if (wv != 0.f) atomicAdd(&zloc[c.y], wv * v.y);
        wv = wfull[r.z]; if (wv != 0.f) atomicAdd(&zloc[c.z], wv * v.z);
        wv = wfull[r.w]; if (wv != 0.f) atomicAdd(&zloc[c.w], wv * v.w);
    }
    __syncthreads();

    float4* dst = (float4*)(z_part + ((size_t)b * SEG + seg) * N);
    dst[tid] = ((const float4*)zloc)[tid];
}

// ---------------------------------------------------------------------------
// Scatter: Z[b][neighbors[b,n]] += sum_sg z_part[b,sg,n]. 131072 threads,
// one global atomicAdd each.
// ---------------------------------------------------------------------------
__global__ __launch_bounds__(512) void scatter_kernel(
    const int* __restrict__ neighbors, const float* __restrict__ z_part,
    float* __restrict__ Z)
{
    const int i = blockIdx.x * 512 + threadIdx.x;   // 256 blocks -> B*N
    const int b = i >> 11, n = i & 2047;
    const float* zp = z_part + (size_t)b * (SEG * N) + n;
    float zv = 0.f;
    #pragma unroll
    for (int sg = 0; sg < SEG; ++sg) zv += zp[sg * N];
    atomicAdd(&Z[(size_t)b * KPAD + neighbors[i]], zv);
}

// ---------------------------------------------------------------------------
// Dense GEMM v3: u_pp[blk] = Z[:, k-range] @ emb[k-range].
// R8 counters (110us, VALU 14.8%, HBM 15%, occ 35%) isolate the bottleneck:
// VMEM *instruction* pressure -- 8 of 12 loads/quad were 64-lane broadcasts
// of the same address (16 useful bytes per VMEM slot), and the 4 emb loads
// were issued even when every row was zero. Fixes:
//  - Z slice staged ONCE per block into LDS (50 KB, coalesced); hot-loop
//    a-reads are same-address ds_read_b128 broadcasts (conflict-free, LDS
//    pipe) -> zero VMEM instructions for Z in the loop.
//  - e-loads made conditional on the wave's 8-row nonzero mask, computed
//    from LDS BEFORE issuing them: ~52% of quads skip all VMEM.
// Effective VMEM/quad: 12 -> ~1.9, all coalesced 1KB emb reads.
// ---------------------------------------------------------------------------
__global__ __launch_bounds__(512) void gemm_kernel(
    const float* __restrict__ Z, const float* __restrict__ emb,
    float* __restrict__ u_pp)
{
    __shared__ float zt[64][200];        // 196 cols + 4 pad (rows stay 16B-aligned)
    const int blk = blockIdx.x;          // 0..511
    const int tid = threadIdx.x;
    const int g   = tid >> 6;            // row-group: rows g*8 .. g*8+7
    const int q   = tid & 63;            // d-quad
    const int k0  = blk * KCH;

    // ---- stage Z[:, k0:k0+KCH) -> LDS (coalesced float4, one pass) ----
    const float4* __restrict__ Z4 = (const float4*)Z;
    for (int x = tid; x < 64 * (KCH / 4); x += 512) {
        const int r = x / (KCH / 4);
        const int c = x - r * (KCH / 4);
        *(float4*)&zt[r][c * 4] = Z4[(size_t)r * (KPAD / 4) + (k0 / 4) + c];
    }
    __syncthreads();

    int kv = ENT - k0;                       // valid entries in this chunk
    kv = kv < 0 ? 0 : (kv > KCH ? KCH : kv); // in {196, 40, 0} -> always %4==0
    const int nq = kv >> 2;

    const float4* __restrict__ e4 = (const float4*)emb;
    float4 acc[8];
    #pragma unroll
    for (int i = 0; i < 8; ++i) acc[i] = make_float4(0.f, 0.f, 0.f, 0.f);

    const int r0 = g * 8;
    for (int t = 0; t < nq; ++t) {
        float4 a[8];
        #pragma unroll
        for (int i = 0; i < 8; ++i)
            a[i] = *(const float4*)&zt[r0 + i][t * 4];   // broadcast ds_read_b128

        unsigned int nz[8], any = 0;
        #pragma unroll
        for (int i = 0; i < 8; ++i) {
            nz[i] = __float_as_uint(a[i].x) | __float_as_uint(a[i].y) |
                    __float_as_uint(a[i].z) | __float_as_uint(a[i].w);
            any |= nz[i];
        }

        if (any) {   // wave-uniform: skip emb VMEM entirely when 8 rows all zero
            const int kk = k0 + t * 4;
            const float4 e0_ = e4[(size_t)(kk + 0) * (D / 4) + q];
            const float4 e1_ = e4[(size_t)(kk + 1) * (D / 4) + q];
            const float4 e2_ = e4[(size_t)(kk + 2) * (D / 4) + q];
            const float4 e3_ = e4[(size_t)(kk + 3) * (D / 4) + q];
            #pragma unroll
            for (int i = 0; i < 8; ++i) {
                if (nz[i]) {
                    acc[i].x += a[i].x*e0_.x + a[i].y*e1_.x + a[i].z*e2_.x + a[i].w*e3_.x;
                    acc[i].y += a[i].x*e0_.y + a[i].y*e1_.y + a[i].z*e2_.y + a[i].w*e3_.y;
                    acc[i].z += a[i].x*e0_.z + a[i].y*e1_.z + a[i].z*e2_.z + a[i].w*e3_.z;
                    acc[i].w += a[i].x*e0_.w + a[i].y*e1_.w + a[i].z*e2_.w + a[i].w*e3_.w;
                }
            }
        }
    }

    float4* dst = (float4*)u_pp + (size_t)blk * (B * D / 4);
    #pragma unroll
    for (int i = 0; i < 8; ++i)
        dst[(r0 + i) * (D / 4) + q] = acc[i];
}

// ---------------------------------------------------------------------------
// Head: stage 1 reduces the 512 GEMM partials; stages 2-4 unchanged.
// ---------------------------------------------------------------------------
__global__ __launch_bounds__(1024) void head_kernel(
    const float* __restrict__ u_pp, const float* __restrict__ sw_part,
    const float* __restrict__ W1, const float* __restrict__ b1,
    const float* __restrict__ W2, const float* __restrict__ b2,
    const float* __restrict__ fc1_w, const float* __restrict__ fc1_b,
    const int* __restrict__ cur_len, float* __restrict__ out)
{
    const int b = blockIdx.x;
    const int t = threadIdx.x & 255;   // output column
    const int s = threadIdx.x >> 8;    // k-split group (0..3)
    __shared__ float red[4][256];
    __shared__ float su[D];
    __shared__ float sy[H];
    __shared__ float sp[H];

    float part = 0.f;
    #pragma unroll 8
    for (int c = s * (GB / 4); c < (s + 1) * (GB / 4); ++c)
        part += u_pp[(size_t)c * (B * D) + b * D + t];
    red[s][t] = part;
    __syncthreads();
    if (s == 0) su[t] = red[0][t] + red[1][t] + red[2][t] + red[3][t];
    __syncthreads();

    part = 0.f;
    #pragma unroll 8
    for (int k = 0; k < 64; ++k) {
        const int d = s * 64 + k;
        part += su[d] * W1[d * H + t];
    }
    red[s][t] = part;
    __syncthreads();
    if (s == 0) {
        float sw = 0.f;
        #pragma unroll
        for (int i = 0; i < SEG; ++i) sw += sw_part[b * SEG + i];
        sy[t] = red[0][t] + red[1][t] + red[2][t] + red[3][t] + sw * b1[t];
    }
    __syncthreads();

    const float invL = 1.f / (float)(*cur_len);
    part = 0.f;
    #pragma unroll 8
    for (int k = 0; k < 64; ++k) {
        const int d = s * 64 + k;
        part += sy[d] * W2[d * H + t];
    }
    red[s][t] = part;
    __syncthreads();
    if (s == 0)
        sp[t] = (red[0][t] + red[1][t] + red[2][t] + red[3][t]) * invL + b2[t];
    __syncthreads();

    part = 0.f;
    #pragma unroll 8
    for (int k = 0; k < 64; ++k) {
        const int d = s * 64 + k;
        part += sp[d] * fc1_w[d * H + t];
    }
    red[s][t] = part;
    __syncthreads();
    if (s == 0) {
        const float v = red[0][t] + red[1][t] + red[2][t] + red[3][t] + fc1_b[t];
        out[(size_t)b * H + t] = fmaxf(v, 0.f);
    }
}

extern "C" void kernel_launch(void* const* d_in, const int* in_sizes, int n_in,
                              void* d_out, int out_size, void* d_ws, size_t ws_size,
                              hipStream_t stream) {
    const int*   neighbors = (const int*)  d_in[0];
    const int*   adj_row   = (const int*)  d_in[1];
    const int*   adj_col   = (const int*)  d_in[2];
    const float* adj_val   = (const float*)d_in[3];
    const float* emb_table = (const float*)d_in[4];
    const float* W1        = (const float*)d_in[5];
    const float* b1        = (const float*)d_in[6];
    const float* W2        = (const float*)d_in[7];
    const float* b2        = (const float*)d_in[8];
    const float* fc1_w     = (const float*)d_in[9];
    const float* fc1_b     = (const float*)d_in[10];
    const int*   cur_len   = (const int*)  d_in[11];
    float*       out       = (float*)d_out;

    // workspace layout (floats), ~67 MB total:
    // [w_part: B*SEG*N][z_part: B*SEG*N][sw_part: B*SEG]
    // [Z: B*KPAD (zeroed in edge_w)][u_pp: GB*B*D]
    float* wp_ws = (float*)d_ws;
    float* zp_ws = wp_ws + (size_t)B * SEG * N;
    float* sw_ws = zp_ws + (size_t)B * SEG * N;
    float* Z_ws  = sw_ws + (size_t)B * SEG;           // 16B-aligned (B*SEG=512)
    float* up_ws = Z_ws  + (size_t)B * KPAD;

    edge_w_kernel<<<dim3(B, SEG), 512, 0, stream>>>(adj_row, adj_col, adj_val,
                                                    cur_len, Z_ws, wp_ws, sw_ws);
    edge_z_kernel<<<dim3(B, SEG), 512, 0, stream>>>(adj_row, adj_col, adj_val,
                                                    wp_ws, zp_ws);
    scatter_kernel<<<(B * N) / 512, 512, 0, stream>>>(neighbors, zp_ws, Z_ws);
    gemm_kernel<<<GB, 512, 0, stream>>>(Z_ws, emb_table, up_ws);
    head_kernel<<<B, 1024, 0, stream>>>(up_ws, sw_ws, W1, b1, W2, b2,
                                        fc1_w, fc1_b, cur_len, out);
}